// Round 1
// baseline (401.054 us; speedup 1.0000x reference)
//
#include <hip/hip_runtime.h>

typedef unsigned short u16;
typedef __bf16 bf16x8 __attribute__((ext_vector_type(8)));
typedef float f32x4 __attribute__((ext_vector_type(4)));
typedef unsigned short u16x8 __attribute__((ext_vector_type(8)));

#define B_ 2
#define T_ 2048
#define K_ 1024
#define H_ 16
#define S_ 64

__device__ __forceinline__ u16 f2bf(float f) {
  unsigned int u = __builtin_bit_cast(unsigned int, f);
  u += 0x7fffu + ((u >> 16) & 1u);
  return (u16)(u >> 16);
}

__device__ __forceinline__ f32x4 MFMA(bf16x8 a, bf16x8 b, f32x4 c) {
  return __builtin_amdgcn_mfma_f32_16x16x32_bf16(a, b, c, 0, 0, 0);
}

template <typename T>
__device__ __forceinline__ void stage16(u16* dst, const T* src);

template <>
__device__ __forceinline__ void stage16<float>(u16* dst, const float* src) {
  const float4* s = (const float4*)src;
  float4 f0 = s[0], f1 = s[1], f2 = s[2], f3 = s[3];
  u16x8 p0, p1;
  p0[0] = f2bf(f0.x); p0[1] = f2bf(f0.y); p0[2] = f2bf(f0.z); p0[3] = f2bf(f0.w);
  p0[4] = f2bf(f1.x); p0[5] = f2bf(f1.y); p0[6] = f2bf(f1.z); p0[7] = f2bf(f1.w);
  p1[0] = f2bf(f2.x); p1[1] = f2bf(f2.y); p1[2] = f2bf(f2.z); p1[3] = f2bf(f2.w);
  p1[4] = f2bf(f3.x); p1[5] = f2bf(f3.y); p1[6] = f2bf(f3.z); p1[7] = f2bf(f3.w);
  *(u16x8*)dst = p0;
  *(u16x8*)(dst + 8) = p1;
}

template <>
__device__ __forceinline__ void stage16<u16>(u16* dst, const u16* src) {
  *(u16x8*)dst = *(const u16x8*)src;
  *(u16x8*)(dst + 8) = *(const u16x8*)(src + 8);
}

// C[M,N] = A[M,K] * B[N,K]^T + bias.  OMODE: 0 = bf16 natural, 1 = bf16 Vt[b,h,s,t], 2 = f32 natural
template <typename TA, typename TB, int OMODE>
__global__ __launch_bounds__(256) void gemm_bt(const TA* __restrict__ A,
                                               const TB* __restrict__ Bm,
                                               const float* __restrict__ bias,
                                               void* __restrict__ Cout,
                                               int M, int N, int K) {
  __shared__ u16 As[128 * 32];
  __shared__ u16 Bs[128 * 32];
  const int bm = blockIdx.x * 128;
  const int bn = blockIdx.y * 128;
  const int tid = threadIdx.x;
  const int w = tid >> 6, lane = tid & 63;
  const int wr = (w >> 1) * 64, wc = (w & 1) * 64;
  const int lr = lane & 15, lk = (lane >> 4) * 8;
  const int g = lane >> 4;
  const int sr = tid >> 1, sc = (tid & 1) * 16;

  f32x4 acc[4][4] = {};

  for (int k0 = 0; k0 < K; k0 += 32) {
    stage16<TA>(&As[sr * 32 + sc], A + (size_t)(bm + sr) * K + k0 + sc);
    stage16<TB>(&Bs[sr * 32 + sc], Bm + (size_t)(bn + sr) * K + k0 + sc);
    __syncthreads();
    bf16x8 af[4], bfr[4];
#pragma unroll
    for (int m = 0; m < 4; ++m)
      af[m] = *(const bf16x8*)&As[(wr + m * 16 + lr) * 32 + lk];
#pragma unroll
    for (int n = 0; n < 4; ++n)
      bfr[n] = *(const bf16x8*)&Bs[(wc + n * 16 + lr) * 32 + lk];
#pragma unroll
    for (int m = 0; m < 4; ++m)
#pragma unroll
      for (int n = 0; n < 4; ++n)
        acc[m][n] = MFMA(af[m], bfr[n], acc[m][n]);
    __syncthreads();
  }

#pragma unroll
  for (int n = 0; n < 4; ++n) {
    const int col = bn + wc + n * 16 + lr;
    const float bv = bias[col];
#pragma unroll
    for (int m = 0; m < 4; ++m) {
#pragma unroll
      for (int r = 0; r < 4; ++r) {
        const int row = bm + wr + m * 16 + g * 4 + r;
        const float v = acc[m][n][r] + bv;
        if (OMODE == 0) {
          ((u16*)Cout)[(size_t)row * N + col] = f2bf(v);
        } else if (OMODE == 1) {
          const int bb = row >> 11, t = row & 2047, hh = col >> 6, ss = col & 63;
          ((u16*)Cout)[(((size_t)(bb * H_ + hh) * S_ + ss) << 11) + t] = f2bf(v);
        } else {
          ((float*)Cout)[(size_t)row * N + col] = v;
        }
      }
    }
  }
}

// Flash attention. Q,K: [B*T, 1024] bf16 (head h at cols h*64..); Vt: [B*H, 64, T] bf16.
// One wave per 16 q-rows, KV tile = 32. Causal, scale = 1/32 (sqrt(K_)).
__global__ __launch_bounds__(256) void attn_fwd(const u16* __restrict__ Q,
                                                const u16* __restrict__ Kb,
                                                const u16* __restrict__ Vt,
                                                u16* __restrict__ O) {
  __shared__ u16 Pl[4][16 * 32];
  const int w = threadIdx.x >> 6, lane = threadIdx.x & 63;
  const int lr = lane & 15, g = lane >> 4;
  const int bh = blockIdx.y;
  const int b = bh >> 4, h = bh & 15;
  const int qw = blockIdx.x * 64 + w * 16;

  const size_t qoff = (size_t)(b * T_ + qw + lr) * K_ + h * S_ + g * 8;
  bf16x8 aq0 = *(const bf16x8*)(Q + qoff);
  bf16x8 aq1 = *(const bf16x8*)(Q + qoff + 32);

  float mrow[4], lrow[4];
  f32x4 o[4] = {};
#pragma unroll
  for (int r = 0; r < 4; ++r) { mrow[r] = -INFINITY; lrow[r] = 0.f; }

  const int nk = (qw + 15) / 32 + 1;
  u16* pw = &Pl[w][0];
  const float scale = 0.03125f;  // 1/sqrt(1024)

  for (int kt = 0; kt < nk; ++kt) {
    const int k0 = kt * 32;
    const size_t koff = (size_t)(b * T_ + k0 + lr) * K_ + h * S_ + g * 8;
    bf16x8 bk00 = *(const bf16x8*)(Kb + koff);
    bf16x8 bk01 = *(const bf16x8*)(Kb + koff + 32);
    bf16x8 bk10 = *(const bf16x8*)(Kb + koff + (size_t)16 * K_);
    bf16x8 bk11 = *(const bf16x8*)(Kb + koff + (size_t)16 * K_ + 32);
    f32x4 s0 = {0.f, 0.f, 0.f, 0.f};
    f32x4 s1 = {0.f, 0.f, 0.f, 0.f};
    s0 = MFMA(aq0, bk00, s0);
    s0 = MFMA(aq1, bk01, s0);
    s1 = MFMA(aq0, bk10, s1);
    s1 = MFMA(aq1, bk11, s1);

#pragma unroll
    for (int r = 0; r < 4; ++r) {
      const int qi = qw + g * 4 + r;
      float v0 = (k0 + lr <= qi) ? s0[r] * scale : -INFINITY;
      float v1 = (k0 + 16 + lr <= qi) ? s1[r] * scale : -INFINITY;
      float mx = fmaxf(v0, v1);
#pragma unroll
      for (int mm = 1; mm < 16; mm <<= 1) mx = fmaxf(mx, __shfl_xor(mx, mm));
      const float mnew = fmaxf(mrow[r], mx);
      const float alpha = __expf(mrow[r] - mnew);
      const float p0 = __expf(v0 - mnew);
      const float p1 = __expf(v1 - mnew);
      float ps = p0 + p1;
#pragma unroll
      for (int mm = 1; mm < 16; mm <<= 1) ps += __shfl_xor(ps, mm);
      lrow[r] = lrow[r] * alpha + ps;
      mrow[r] = mnew;
      o[0][r] *= alpha; o[1][r] *= alpha; o[2][r] *= alpha; o[3][r] *= alpha;
      pw[(g * 4 + r) * 32 + lr] = f2bf(p0);
      pw[(g * 4 + r) * 32 + 16 + lr] = f2bf(p1);
    }

    asm volatile("s_waitcnt lgkmcnt(0)" ::: "memory");
    bf16x8 ap = *(const bf16x8*)(pw + lr * 32 + g * 8);
    const size_t voff = (size_t)(bh * S_ + lr) * T_ + k0 + g * 8;
    o[0] = MFMA(ap, *(const bf16x8*)(Vt + voff), o[0]);
    o[1] = MFMA(ap, *(const bf16x8*)(Vt + voff + (size_t)16 * T_), o[1]);
    o[2] = MFMA(ap, *(const bf16x8*)(Vt + voff + (size_t)32 * T_), o[2]);
    o[3] = MFMA(ap, *(const bf16x8*)(Vt + voff + (size_t)48 * T_), o[3]);
    asm volatile("" ::: "memory");
  }

#pragma unroll
  for (int r = 0; r < 4; ++r) {
    const float inv = 1.f / lrow[r];
    const size_t row = (size_t)(b * T_ + qw + g * 4 + r);
#pragma unroll
    for (int dn = 0; dn < 4; ++dn) {
      O[row * K_ + h * S_ + dn * 16 + lr] = f2bf(o[dn][r] * inv);
    }
  }
}

extern "C" void kernel_launch(void* const* d_in, const int* in_sizes, int n_in,
                              void* d_out, int out_size, void* d_ws, size_t ws_size,
                              hipStream_t stream) {
  (void)in_sizes; (void)n_in; (void)out_size; (void)ws_size;
  const float* x  = (const float*)d_in[0];
  const float* Wq = (const float*)d_in[1];
  const float* bq = (const float*)d_in[2];
  const float* Wk = (const float*)d_in[3];
  const float* bk = (const float*)d_in[4];
  const float* Wv = (const float*)d_in[5];
  const float* bv = (const float*)d_in[6];
  const float* Wo = (const float*)d_in[7];
  const float* bo = (const float*)d_in[8];
  float* out = (float*)d_out;

  const size_t MK = (size_t)B_ * T_ * K_;  // 4 Mi elements
  u16* Qb  = (u16*)d_ws;
  u16* Kbf = Qb + MK;
  u16* Vtb = Kbf + MK;
  u16* AO  = Vtb + MK;

  dim3 blk(256);
  dim3 gg(32, 8);  // M/128, N/128
  gemm_bt<float, float, 0><<<gg, blk, 0, stream>>>(x, Wq, bq, Qb, B_ * T_, K_, K_);
  gemm_bt<float, float, 0><<<gg, blk, 0, stream>>>(x, Wk, bk, Kbf, B_ * T_, K_, K_);
  gemm_bt<float, float, 1><<<gg, blk, 0, stream>>>(x, Wv, bv, Vtb, B_ * T_, K_, K_);
  attn_fwd<<<dim3(T_ / 64, B_ * H_), blk, 0, stream>>>(Qb, Kbf, Vtb, AO);
  gemm_bt<u16, float, 2><<<gg, blk, 0, stream>>>(AO, Wo, bo, out, B_ * T_, K_, K_);
}

// Round 2
// 261.861 us; speedup vs baseline: 1.5316x; 1.5316x over previous
//
#include <hip/hip_runtime.h>

typedef unsigned short u16;
typedef unsigned int u32;
typedef __bf16 bf16x8 __attribute__((ext_vector_type(8)));
typedef float f32x4 __attribute__((ext_vector_type(4)));
typedef unsigned short u16x8 __attribute__((ext_vector_type(8)));

#define B_ 2
#define T_ 2048
#define K_ 1024
#define H_ 16
#define S_ 64

__device__ __forceinline__ u16 f2bf(float f) {
  unsigned int u = __builtin_bit_cast(unsigned int, f);
  u += 0x7fffu + ((u >> 16) & 1u);
  return (u16)(u >> 16);
}

__device__ __forceinline__ f32x4 MFMA(bf16x8 a, bf16x8 b, f32x4 c) {
  return __builtin_amdgcn_mfma_f32_16x16x32_bf16(a, b, c, 0, 0, 0);
}

__device__ __forceinline__ void gld16(const void* g, void* l) {
  __builtin_amdgcn_global_load_lds((const __attribute__((address_space(1))) void*)g,
                                   (__attribute__((address_space(3))) void*)l, 16, 0, 0);
}

// ---------------- fp32 -> bf16 conversion (elementwise, vectorized) ----------------
__global__ __launch_bounds__(256) void cvt_f32_bf16(const float* __restrict__ in,
                                                    u16* __restrict__ out, int n8) {
  int i = blockIdx.x * blockDim.x + threadIdx.x;
  if (i >= n8) return;
  const float4* s = (const float4*)(in + (size_t)i * 8);
  float4 f0 = s[0], f1 = s[1];
  u16x8 p;
  p[0] = f2bf(f0.x); p[1] = f2bf(f0.y); p[2] = f2bf(f0.z); p[3] = f2bf(f0.w);
  p[4] = f2bf(f1.x); p[5] = f2bf(f1.y); p[6] = f2bf(f1.z); p[7] = f2bf(f1.w);
  *(u16x8*)(out + (size_t)i * 8) = p;
}

// ---------------- GEMM: C[M,N] = A[M,K] * B[N,K]^T + bias ----------------
template <typename T>
__device__ __forceinline__ void stage16(u16* dst, const T* src);

template <>
__device__ __forceinline__ void stage16<float>(u16* dst, const float* src) {
  const float4* s = (const float4*)src;
  float4 f0 = s[0], f1 = s[1], f2 = s[2], f3 = s[3];
  u16x8 p0, p1;
  p0[0] = f2bf(f0.x); p0[1] = f2bf(f0.y); p0[2] = f2bf(f0.z); p0[3] = f2bf(f0.w);
  p0[4] = f2bf(f1.x); p0[5] = f2bf(f1.y); p0[6] = f2bf(f1.z); p0[7] = f2bf(f1.w);
  p1[0] = f2bf(f2.x); p1[1] = f2bf(f2.y); p1[2] = f2bf(f2.z); p1[3] = f2bf(f2.w);
  p1[4] = f2bf(f3.x); p1[5] = f2bf(f3.y); p1[6] = f2bf(f3.z); p1[7] = f2bf(f3.w);
  *(u16x8*)dst = p0;
  *(u16x8*)(dst + 8) = p1;
}

template <>
__device__ __forceinline__ void stage16<u16>(u16* dst, const u16* src) {
  *(u16x8*)dst = *(const u16x8*)src;
  *(u16x8*)(dst + 8) = *(const u16x8*)(src + 8);
}

// OMODE: 0 = bf16 natural, 1 = bf16 Vt[b,h,s,t], 2 = f32 natural
template <typename TA, typename TB, int OMODE>
__global__ __launch_bounds__(256) void gemm_bt(const TA* __restrict__ A,
                                               const TB* __restrict__ Bm,
                                               const float* __restrict__ bias,
                                               void* __restrict__ Cout,
                                               int M, int N, int K) {
  __shared__ u16 As[128 * 32];
  __shared__ u16 Bs[128 * 32];
  const int bm = blockIdx.x * 128;
  const int bn = blockIdx.y * 128;
  const int tid = threadIdx.x;
  const int w = tid >> 6, lane = tid & 63;
  const int wr = (w >> 1) * 64, wc = (w & 1) * 64;
  const int lr = lane & 15, lk = (lane >> 4) * 8;
  const int g = lane >> 4;
  const int sr = tid >> 1, sc = (tid & 1) * 16;

  f32x4 acc[4][4] = {};

  for (int k0 = 0; k0 < K; k0 += 32) {
    stage16<TA>(&As[sr * 32 + sc], A + (size_t)(bm + sr) * K + k0 + sc);
    stage16<TB>(&Bs[sr * 32 + sc], Bm + (size_t)(bn + sr) * K + k0 + sc);
    __syncthreads();
    bf16x8 af[4], bfr[4];
#pragma unroll
    for (int m = 0; m < 4; ++m)
      af[m] = *(const bf16x8*)&As[(wr + m * 16 + lr) * 32 + lk];
#pragma unroll
    for (int n = 0; n < 4; ++n)
      bfr[n] = *(const bf16x8*)&Bs[(wc + n * 16 + lr) * 32 + lk];
#pragma unroll
    for (int m = 0; m < 4; ++m)
#pragma unroll
      for (int n = 0; n < 4; ++n)
        acc[m][n] = MFMA(af[m], bfr[n], acc[m][n]);
    __syncthreads();
  }

#pragma unroll
  for (int n = 0; n < 4; ++n) {
    const int col = bn + wc + n * 16 + lr;
    const float bv = bias[col];
#pragma unroll
    for (int m = 0; m < 4; ++m) {
#pragma unroll
      for (int r = 0; r < 4; ++r) {
        const int row = bm + wr + m * 16 + g * 4 + r;
        const float v = acc[m][n][r] + bv;
        if (OMODE == 0) {
          ((u16*)Cout)[(size_t)row * N + col] = f2bf(v);
        } else if (OMODE == 1) {
          const int bb = row >> 11, t = row & 2047, hh = col >> 6, ss = col & 63;
          ((u16*)Cout)[(((size_t)(bb * H_ + hh) * S_ + ss) << 11) + t] = f2bf(v);
        } else {
          ((float*)Cout)[(size_t)row * N + col] = v;
        }
      }
    }
  }
}

// ---------------- Flash attention, swapped-QK^T, KVBLK=64 ----------------
// Q,K: [B*T, 1024] bf16 (head h at cols h*64..); Vt: [B*H, 64, T] bf16.
// Block: 4 waves x 16 q-rows = 64 q. K tile (64 kv x 64 d) staged in LDS,
// double-buffered, XOR-swizzled (slot ^= row&7, 16B slots) via pre-swizzled
// global source. Swapped QK^T: mfma(A=K, B=Q) -> S^T[kv][q]; each lane owns
// one q-row -> softmax is 15 fmax + 2 shfl. P goes through per-wave swizzled
// LDS back to A-fragment layout for PV. V read from global (L2-resident).
__global__ __launch_bounds__(256) void attn_fwd(const u16* __restrict__ Q,
                                                const u16* __restrict__ Kb,
                                                const u16* __restrict__ Vt,
                                                u16* __restrict__ O) {
  __shared__ u16 Ks[2][64 * 64];   // 2 x 8 KB, row stride 128 B (8 x 16B slots)
  __shared__ u32 Ps[4][16 * 32];   // per-wave P: 16 q-rows x 32 u32 (64 bf16)
  const int tid = threadIdx.x;
  const int w = tid >> 6, lane = tid & 63;
  const int qh = lane & 15;        // lane's q within wave tile; also frag row
  const int g = lane >> 4;
  const int bh = blockIdx.y;
  const int b = bh >> 4, h = bh & 15;
  const int qb = blockIdx.x * 64;
  const int qw = qb + w * 16;
  const int myq = qw + qh;
  const float scale = 0.03125f;    // 1/sqrt(1024)

  // Q fragments (B-operand of swapped QK^T): Q[qw+qh][dims g*8.. , 32+g*8..]
  const size_t qoff = (size_t)(b * T_ + qw + qh) * K_ + h * S_ + g * 8;
  const bf16x8 bq0 = *(const bf16x8*)(Q + qoff);
  const bf16x8 bq1 = *(const bf16x8*)(Q + qoff + 32);

  // stage K tile [k0..k0+63][0..63] into Ks[buf], pre-swizzled source
  const int srow = lane >> 3;                 // 0..7
  const int sslot = (lane & 7) ^ srow;        // global slot fetched by this lane
  auto stageK = [&](int buf, int k0) {
#pragma unroll
    for (int i = 0; i < 2; ++i) {
      const int rbase = w * 16 + i * 8;
      const u16* src = Kb + (size_t)(b * T_ + k0 + rbase + srow) * K_ + h * S_ + sslot * 8;
      gld16(src, &Ks[buf][rbase * 64]);
    }
  };

  const int nk = qb / 64 + 1;
  stageK(0, 0);
  asm volatile("s_waitcnt vmcnt(0)" ::: "memory");
  __syncthreads();

  float m = -INFINITY, lsum = 0.f;
  f32x4 o[4] = {};
  u32* pr = &Ps[w][qh * 32];
  const int sx = (qh & 7) << 2;    // P-LDS swizzle (bits 2-4 of u32 index)
  const int ksw = qh & 7;          // K-LDS slot swizzle for frag reads

  for (int kt = 0; kt < nk; ++kt) {
    const int k0 = kt * 64;
    const int cur = kt & 1;
    if (kt + 1 < nk) stageK(cur ^ 1, k0 + 64);

    // QK^T (swapped): s[a] = S^T tile rows 16a..16a+15, col q
    f32x4 s[4] = {};
#pragma unroll
    for (int a = 0; a < 4; ++a) {
      const u16* kr = &Ks[cur][(a * 16 + qh) * 64];
      const bf16x8 kf0 = *(const bf16x8*)(kr + ((g ^ ksw) * 8));
      const bf16x8 kf1 = *(const bf16x8*)(kr + (((4 + g) ^ ksw) * 8));
      s[a] = MFMA(kf0, bq0, s[a]);
      s[a] = MFMA(kf1, bq1, s[a]);
    }

    // mask + scale; lane-local softmax over its 16 kv values
    float p[4][4];
    float vmax = -INFINITY;
#pragma unroll
    for (int a = 0; a < 4; ++a)
#pragma unroll
      for (int r = 0; r < 4; ++r) {
        const int kv = k0 + a * 16 + g * 4 + r;
        const float v = (kv <= myq) ? s[a][r] * scale : -INFINITY;
        p[a][r] = v;
        vmax = fmaxf(vmax, v);
      }
    vmax = fmaxf(vmax, __shfl_xor(vmax, 16));
    vmax = fmaxf(vmax, __shfl_xor(vmax, 32));
    const float mnew = fmaxf(m, vmax);
    const float alpha = __expf(m - mnew);
    m = mnew;
    float ls = 0.f;
#pragma unroll
    for (int a = 0; a < 4; ++a)
#pragma unroll
      for (int r = 0; r < 4; ++r) {
        p[a][r] = __expf(p[a][r] - mnew);
        ls += p[a][r];
      }
    ls += __shfl_xor(ls, 16);
    ls += __shfl_xor(ls, 32);
    lsum = lsum * alpha + ls;

    // rescale O rows (row q = qw + 4g + r; alpha lives in lane 4g+r)
    float aR[4];
#pragma unroll
    for (int r = 0; r < 4; ++r) aR[r] = __shfl(alpha, 4 * g + r);
#pragma unroll
    for (int n = 0; n < 4; ++n)
#pragma unroll
      for (int r = 0; r < 4; ++r) o[n][r] *= aR[r];

    // P -> per-wave LDS (row qh, u32 idx (8a+2g+h) ^ sx), then A-frag reads
#pragma unroll
    for (int a = 0; a < 4; ++a) {
      const u32 u0 = (u32)f2bf(p[a][0]) | ((u32)f2bf(p[a][1]) << 16);
      const u32 u1 = (u32)f2bf(p[a][2]) | ((u32)f2bf(p[a][3]) << 16);
      const int idx = (8 * a + 2 * g) ^ sx;
      uint2 uu; uu.x = u0; uu.y = u1;
      *(uint2*)&pr[idx] = uu;
    }
#pragma unroll
    for (int c = 0; c < 2; ++c) {
      const bf16x8 pa = *(const bf16x8*)&pr[(16 * c + 4 * g) ^ sx];
      const size_t vbase = (size_t)(bh * S_ + qh) * T_ + k0 + c * 32 + g * 8;
#pragma unroll
      for (int n = 0; n < 4; ++n)
        o[n] = MFMA(pa, *(const bf16x8*)(Vt + vbase + (size_t)(16 * n) * T_), o[n]);
    }

    asm volatile("s_waitcnt vmcnt(0)" ::: "memory");
    __syncthreads();
  }

  const float inv = 1.f / lsum;
  float iR[4];
#pragma unroll
  for (int r = 0; r < 4; ++r) iR[r] = __shfl(inv, 4 * g + r);
#pragma unroll
  for (int r = 0; r < 4; ++r) {
    const size_t row = (size_t)(b * T_ + qw + 4 * g + r);
#pragma unroll
    for (int n = 0; n < 4; ++n)
      O[row * K_ + h * S_ + n * 16 + qh] = f2bf(o[n][r] * iR[r]);
  }
}

extern "C" void kernel_launch(void* const* d_in, const int* in_sizes, int n_in,
                              void* d_out, int out_size, void* d_ws, size_t ws_size,
                              hipStream_t stream) {
  (void)in_sizes; (void)n_in; (void)out_size;
  const float* x  = (const float*)d_in[0];
  const float* Wq = (const float*)d_in[1];
  const float* bq = (const float*)d_in[2];
  const float* Wk = (const float*)d_in[3];
  const float* bk = (const float*)d_in[4];
  const float* Wv = (const float*)d_in[5];
  const float* bv = (const float*)d_in[6];
  const float* Wo = (const float*)d_in[7];
  const float* bo = (const float*)d_in[8];
  float* out = (float*)d_out;

  const size_t MK = (size_t)B_ * T_ * K_;   // 4 Mi
  const size_t WK = (size_t)K_ * K_;        // 1 Mi
  u16* Qb  = (u16*)d_ws;
  u16* Kbf = Qb + MK;
  u16* Vtb = Kbf + MK;
  u16* AO  = Vtb + MK;

  dim3 blk(256);
  dim3 gg(32, 8);   // M/128, N/128

  const bool cv = ws_size >= (size_t)(MK * 5 + WK * 4) * sizeof(u16);
  if (cv) {
    u16* xb  = AO + MK;
    u16* Wqb = xb + MK;
    u16* Wkb = Wqb + WK;
    u16* Wvb = Wkb + WK;
    u16* Wob = Wvb + WK;
    cvt_f32_bf16<<<dim3((int)(MK / 8 / 256)), blk, 0, stream>>>(x, xb, (int)(MK / 8));
    cvt_f32_bf16<<<dim3((int)(WK / 8 / 256)), blk, 0, stream>>>(Wq, Wqb, (int)(WK / 8));
    cvt_f32_bf16<<<dim3((int)(WK / 8 / 256)), blk, 0, stream>>>(Wk, Wkb, (int)(WK / 8));
    cvt_f32_bf16<<<dim3((int)(WK / 8 / 256)), blk, 0, stream>>>(Wv, Wvb, (int)(WK / 8));
    cvt_f32_bf16<<<dim3((int)(WK / 8 / 256)), blk, 0, stream>>>(Wo, Wob, (int)(WK / 8));
    gemm_bt<u16, u16, 0><<<gg, blk, 0, stream>>>(xb, Wqb, bq, Qb, B_ * T_, K_, K_);
    gemm_bt<u16, u16, 0><<<gg, blk, 0, stream>>>(xb, Wkb, bk, Kbf, B_ * T_, K_, K_);
    gemm_bt<u16, u16, 1><<<gg, blk, 0, stream>>>(xb, Wvb, bv, Vtb, B_ * T_, K_, K_);
    attn_fwd<<<dim3(T_ / 64, B_ * H_), blk, 0, stream>>>(Qb, Kbf, Vtb, AO);
    gemm_bt<u16, u16, 2><<<gg, blk, 0, stream>>>(AO, Wob, bo, out, B_ * T_, K_, K_);
  } else {
    gemm_bt<float, float, 0><<<gg, blk, 0, stream>>>(x, Wq, bq, Qb, B_ * T_, K_, K_);
    gemm_bt<float, float, 0><<<gg, blk, 0, stream>>>(x, Wk, bk, Kbf, B_ * T_, K_, K_);
    gemm_bt<float, float, 1><<<gg, blk, 0, stream>>>(x, Wv, bv, Vtb, B_ * T_, K_, K_);
    attn_fwd<<<dim3(T_ / 64, B_ * H_), blk, 0, stream>>>(Qb, Kbf, Vtb, AO);
    gemm_bt<u16, float, 2><<<gg, blk, 0, stream>>>(AO, Wo, bo, out, B_ * T_, K_, K_);
  }
}

// Round 3
// 161.148 us; speedup vs baseline: 2.4887x; 1.6250x over previous
//
#include <hip/hip_runtime.h>

typedef unsigned short u16;
typedef unsigned int u32;
typedef __bf16 bf16x8 __attribute__((ext_vector_type(8)));
typedef float f32x4 __attribute__((ext_vector_type(4)));
typedef unsigned short u16x8 __attribute__((ext_vector_type(8)));

#define B_ 2
#define T_ 2048
#define K_ 1024
#define H_ 16
#define S_ 64
#define MKC 4194304  // B_*T_*K_

__device__ __forceinline__ u16 f2bf(float f) {
  unsigned int u = __builtin_bit_cast(unsigned int, f);
  u += 0x7fffu + ((u >> 16) & 1u);
  return (u16)(u >> 16);
}

__device__ __forceinline__ f32x4 MFMA(bf16x8 a, bf16x8 b, f32x4 c) {
  return __builtin_amdgcn_mfma_f32_16x16x32_bf16(a, b, c, 0, 0, 0);
}

__device__ __forceinline__ void gld16(const void* g, void* l) {
  __builtin_amdgcn_global_load_lds((const __attribute__((address_space(1))) void*)g,
                                   (__attribute__((address_space(3))) void*)l, 16, 0, 0);
}

// ---------------- fp32 -> bf16 conversions ----------------
__global__ __launch_bounds__(256) void cvt_f32_bf16(const float* __restrict__ in,
                                                    u16* __restrict__ out, int n8) {
  int i = blockIdx.x * blockDim.x + threadIdx.x;
  if (i >= n8) return;
  const float4* s = (const float4*)(in + (size_t)i * 8);
  float4 f0 = s[0], f1 = s[1];
  u16x8 p;
  p[0] = f2bf(f0.x); p[1] = f2bf(f0.y); p[2] = f2bf(f0.z); p[3] = f2bf(f0.w);
  p[4] = f2bf(f1.x); p[5] = f2bf(f1.y); p[6] = f2bf(f1.z); p[7] = f2bf(f1.w);
  *(u16x8*)(out + (size_t)i * 8) = p;
}

// 4 weight matrices (1 Mi fp32 each) -> contiguous bf16
__global__ __launch_bounds__(256) void cvt_w4(const float* __restrict__ W0,
                                              const float* __restrict__ W1,
                                              const float* __restrict__ W2,
                                              const float* __restrict__ W3,
                                              u16* __restrict__ out) {
  int i = blockIdx.x * blockDim.x + threadIdx.x;  // 8-elem units, 4*131072 total
  const int sel = i >> 17;                        // uniform per block
  const float* p = sel == 0 ? W0 : sel == 1 ? W1 : sel == 2 ? W2 : W3;
  const int r = i & 131071;
  const float4* s = (const float4*)(p + (size_t)r * 8);
  float4 f0 = s[0], f1 = s[1];
  u16x8 o;
  o[0] = f2bf(f0.x); o[1] = f2bf(f0.y); o[2] = f2bf(f0.z); o[3] = f2bf(f0.w);
  o[4] = f2bf(f1.x); o[5] = f2bf(f1.y); o[6] = f2bf(f1.z); o[7] = f2bf(f1.w);
  *(u16x8*)(out + (size_t)i * 8) = o;
}

// ---------------- GEMM (bf16 in, gld16 staging): C = A[M,K] * B[N,K]^T + bias ----
// OMODE 3: fused QKV epilogue (N=3072): sel = bn>>10 -> Q,K natural bf16; V -> Vt[b,h,s,t]
// OMODE 2: f32 natural output, bias b0
template <int OMODE>
__global__ __launch_bounds__(256) void gemm16(const u16* __restrict__ A,
                                              const u16* __restrict__ Bm,
                                              const float* __restrict__ b0,
                                              const float* __restrict__ b1,
                                              const float* __restrict__ b2,
                                              void* __restrict__ C0,
                                              int M, int N, int K) {
  __shared__ u16 As[128 * 32];
  __shared__ u16 Bs[128 * 32];
  const int bm = blockIdx.x * 128;
  const int bn = blockIdx.y * 128;
  const int tid = threadIdx.x;
  const int w = tid >> 6, lane = tid & 63;
  const int wr = (w >> 1) * 64, wc = (w & 1) * 64;
  const int lr = lane & 15, g = lane >> 4;
  const int lk = g * 8;
  const int srow = lane >> 2, scol = (lane & 3) * 8;  // stage mapping: 16B/lane

  f32x4 acc[4][4] = {};

  for (int k0 = 0; k0 < K; k0 += 32) {
#pragma unroll
    for (int i = 0; i < 2; ++i) {
      const int rbase = (i * 4 + w) * 16;
      gld16(A + (size_t)(bm + rbase + srow) * K + k0 + scol, &As[rbase * 32]);
      gld16(Bm + (size_t)(bn + rbase + srow) * K + k0 + scol, &Bs[rbase * 32]);
    }
    asm volatile("s_waitcnt vmcnt(0)" ::: "memory");
    __syncthreads();
    bf16x8 af[4], bfr[4];
#pragma unroll
    for (int m = 0; m < 4; ++m)
      af[m] = *(const bf16x8*)&As[(wr + m * 16 + lr) * 32 + lk];
#pragma unroll
    for (int n = 0; n < 4; ++n)
      bfr[n] = *(const bf16x8*)&Bs[(wc + n * 16 + lr) * 32 + lk];
#pragma unroll
    for (int m = 0; m < 4; ++m)
#pragma unroll
      for (int n = 0; n < 4; ++n)
        acc[m][n] = MFMA(af[m], bfr[n], acc[m][n]);
    __syncthreads();
  }

  const int sel = bn >> 10;  // uniform per block (128-tile never crosses 1024)
  const float* bp = (OMODE == 2) ? b0 : (sel == 0 ? b0 : sel == 1 ? b1 : b2);
#pragma unroll
  for (int n = 0; n < 4; ++n) {
    const int col = bn + wc + n * 16 + lr;
    const float bv = bp[(OMODE == 2) ? col : (col & 1023)];
#pragma unroll
    for (int m = 0; m < 4; ++m) {
#pragma unroll
      for (int r = 0; r < 4; ++r) {
        const int row = bm + wr + m * 16 + g * 4 + r;
        const float v = acc[m][n][r] + bv;
        if (OMODE == 2) {
          ((float*)C0)[(size_t)row * N + col] = v;
        } else {
          u16* dst = (u16*)C0;
          const int cc = col & 1023;
          if (sel == 2) {
            const int bb = row >> 11, t = row & 2047, hh = cc >> 6, ss = cc & 63;
            dst[(size_t)2 * MKC + (((size_t)(bb * H_ + hh) * S_ + ss) << 11) + t] = f2bf(v);
          } else {
            dst[(size_t)sel * MKC + (size_t)row * 1024 + cc] = f2bf(v);
          }
        }
      }
    }
  }
}

// ---------------- Flash attention, swapped-QK^T, KVBLK=64, K+V in LDS ----------------
__global__ __launch_bounds__(256) void attn_fwd(const u16* __restrict__ Q,
                                                const u16* __restrict__ Kb,
                                                const u16* __restrict__ Vt,
                                                u16* __restrict__ O) {
  __shared__ u16 Ks[2][64 * 64];   // 2 x 8 KB, rows 128 B (8 x 16B slots), XOR-swizzled
  __shared__ u16 Vs[2][64 * 64];   // same layout: [s(64)][t(64)]
  __shared__ u32 Ps[4][16 * 32];   // per-wave P
  const int tid = threadIdx.x;
  const int w = tid >> 6, lane = tid & 63;
  const int qh = lane & 15;
  const int g = lane >> 4;
  const int bh = blockIdx.y;
  const int b = bh >> 4, h = bh & 15;
  const int qb = blockIdx.x * 64;
  const int qw = qb + w * 16;
  const int myq = qw + qh;
  const float scale = 0.03125f;    // 1/sqrt(1024)

  const size_t qoff = (size_t)(b * T_ + qw + qh) * K_ + h * S_ + g * 8;
  const bf16x8 bq0 = *(const bf16x8*)(Q + qoff);
  const bf16x8 bq1 = *(const bf16x8*)(Q + qoff + 32);

  // staging: per wave 2x8 rows each of K and V; pre-swizzled global source
  const int srow = lane >> 3;            // 0..7
  const int sslot = (lane & 7) ^ srow;
  auto stage = [&](int buf, int k0) {
#pragma unroll
    for (int i = 0; i < 2; ++i) {
      const int rbase = w * 16 + i * 8;
      gld16(Kb + (size_t)(b * T_ + k0 + rbase + srow) * K_ + h * S_ + sslot * 8,
            &Ks[buf][rbase * 64]);
      gld16(Vt + (size_t)(bh * S_ + rbase + srow) * T_ + k0 + sslot * 8,
            &Vs[buf][rbase * 64]);
    }
  };

  const int nk = qb / 64 + 1;
  stage(0, 0);
  asm volatile("s_waitcnt vmcnt(0)" ::: "memory");
  __syncthreads();

  float m = -INFINITY, lsum = 0.f;
  f32x4 o[4] = {};
  u32* pr = &Ps[w][qh * 32];
  const int sx = (qh & 7) << 2;
  const int ksw = qh & 7;

  for (int kt = 0; kt < nk; ++kt) {
    const int k0 = kt * 64;
    const int cur = kt & 1;
    if (kt + 1 < nk) stage(cur ^ 1, k0 + 64);

    // QK^T (swapped): S^T[kv][q]
    f32x4 s[4] = {};
#pragma unroll
    for (int a = 0; a < 4; ++a) {
      const u16* kr = &Ks[cur][(a * 16 + qh) * 64];
      const bf16x8 kf0 = *(const bf16x8*)(kr + ((g ^ ksw) * 8));
      const bf16x8 kf1 = *(const bf16x8*)(kr + (((4 + g) ^ ksw) * 8));
      s[a] = MFMA(kf0, bq0, s[a]);
      s[a] = MFMA(kf1, bq1, s[a]);
    }

    float p[4][4];
    float vmax = -INFINITY;
#pragma unroll
    for (int a = 0; a < 4; ++a)
#pragma unroll
      for (int r = 0; r < 4; ++r) {
        const int kv = k0 + a * 16 + g * 4 + r;
        const float v = (kv <= myq) ? s[a][r] * scale : -INFINITY;
        p[a][r] = v;
        vmax = fmaxf(vmax, v);
      }
    vmax = fmaxf(vmax, __shfl_xor(vmax, 16));
    vmax = fmaxf(vmax, __shfl_xor(vmax, 32));

    // defer-max (T13): rescale only when max grew materially
    if (__any(vmax > m + 8.f)) {
      const float mnew = fmaxf(m, vmax);
      const float alpha = __expf(m - mnew);
      m = mnew;
      lsum *= alpha;
      float aR[4];
#pragma unroll
      for (int r = 0; r < 4; ++r) aR[r] = __shfl(alpha, 4 * g + r);
#pragma unroll
      for (int n = 0; n < 4; ++n)
#pragma unroll
        for (int r = 0; r < 4; ++r) o[n][r] *= aR[r];
    }

    float ls = 0.f;
#pragma unroll
    for (int a = 0; a < 4; ++a)
#pragma unroll
      for (int r = 0; r < 4; ++r) {
        p[a][r] = __expf(p[a][r] - m);
        ls += p[a][r];
      }
    ls += __shfl_xor(ls, 16);
    ls += __shfl_xor(ls, 32);
    lsum += ls;

    // P -> per-wave LDS (swizzled), read back as A-frags
#pragma unroll
    for (int a = 0; a < 4; ++a) {
      const u32 u0 = (u32)f2bf(p[a][0]) | ((u32)f2bf(p[a][1]) << 16);
      const u32 u1 = (u32)f2bf(p[a][2]) | ((u32)f2bf(p[a][3]) << 16);
      uint2 uu; uu.x = u0; uu.y = u1;
      *(uint2*)&pr[(8 * a + 2 * g) ^ sx] = uu;
    }
#pragma unroll
    for (int c = 0; c < 2; ++c) {
      const bf16x8 pa = *(const bf16x8*)&pr[(16 * c + 4 * g) ^ sx];
#pragma unroll
      for (int n = 0; n < 4; ++n) {
        const bf16x8 vf =
            *(const bf16x8*)(&Vs[cur][(16 * n + qh) * 64] + (((c * 4 + g) ^ ksw) * 8));
        o[n] = MFMA(pa, vf, o[n]);
      }
    }

    asm volatile("s_waitcnt vmcnt(0)" ::: "memory");
    __syncthreads();
  }

  const float inv = 1.f / lsum;
  float iR[4];
#pragma unroll
  for (int r = 0; r < 4; ++r) iR[r] = __shfl(inv, 4 * g + r);
#pragma unroll
  for (int r = 0; r < 4; ++r) {
    const size_t row = (size_t)(b * T_ + qw + 4 * g + r);
#pragma unroll
    for (int n = 0; n < 4; ++n)
      O[row * K_ + h * S_ + n * 16 + qh] = f2bf(o[n][r] * iR[r]);
  }
}

extern "C" void kernel_launch(void* const* d_in, const int* in_sizes, int n_in,
                              void* d_out, int out_size, void* d_ws, size_t ws_size,
                              hipStream_t stream) {
  (void)in_sizes; (void)n_in; (void)out_size; (void)ws_size;
  const float* x  = (const float*)d_in[0];
  const float* Wq = (const float*)d_in[1];
  const float* bq = (const float*)d_in[2];
  const float* Wk = (const float*)d_in[3];
  const float* bk = (const float*)d_in[4];
  const float* Wv = (const float*)d_in[5];
  const float* bv = (const float*)d_in[6];
  const float* Wo = (const float*)d_in[7];
  const float* bo = (const float*)d_in[8];
  float* out = (float*)d_out;

  const size_t MK = (size_t)MKC;            // 4 Mi
  const size_t WK = (size_t)K_ * K_;        // 1 Mi
  u16* Qb  = (u16*)d_ws;                    // Q | K | Vt contiguous (gemm16<3> dst)
  u16* Kbf = Qb + MK;
  u16* Vtb = Kbf + MK;
  u16* AO  = Vtb + MK;
  u16* xb  = AO + MK;
  u16* Wqkv = xb + MK;                      // Wq|Wk|Wv|Wo bf16 contiguous
  u16* Wob  = Wqkv + 3 * WK;

  dim3 blk(256);
  cvt_f32_bf16<<<dim3(2048), blk, 0, stream>>>(x, xb, (int)(MK / 8));
  cvt_w4<<<dim3(2048), blk, 0, stream>>>(Wq, Wk, Wv, Wo, Wqkv);
  gemm16<3><<<dim3(32, 24), blk, 0, stream>>>(xb, Wqkv, bq, bk, bv, Qb,
                                              B_ * T_, 3 * K_, K_);
  attn_fwd<<<dim3(T_ / 64, B_ * H_), blk, 0, stream>>>(Qb, Kbf, Vtb, AO);
  gemm16<2><<<dim3(32, 8), blk, 0, stream>>>(AO, Wob, bo, bo, bo, out,
                                             B_ * T_, K_, K_);
}

// Round 4
// 116.345 us; speedup vs baseline: 3.4471x; 1.3851x over previous
//
#include <hip/hip_runtime.h>

typedef unsigned short u16;
typedef unsigned int u32;
typedef __bf16 bf16x8 __attribute__((ext_vector_type(8)));
typedef float f32x4 __attribute__((ext_vector_type(4)));
typedef unsigned short u16x8 __attribute__((ext_vector_type(8)));

#define B_ 2
#define T_ 2048
#define K_ 1024
#define H_ 16
#define S_ 64
#define MKC 4194304   // B_*T_*K_
#define QSCALE 0.04508422f  // log2(e)/32  -> QK logits land in log2-domain

__device__ __forceinline__ u16 f2bf(float f) {
  unsigned int u = __builtin_bit_cast(unsigned int, f);
  u += 0x7fffu + ((u >> 16) & 1u);
  return (u16)(u >> 16);
}

__device__ __forceinline__ f32x4 MFMA(bf16x8 a, bf16x8 b, f32x4 c) {
  return __builtin_amdgcn_mfma_f32_16x16x32_bf16(a, b, c, 0, 0, 0);
}

__device__ __forceinline__ void gld16(const void* g, void* l) {
  __builtin_amdgcn_global_load_lds((const __attribute__((address_space(1))) void*)g,
                                   (__attribute__((address_space(3))) void*)l, 16, 0, 0);
}

// ---------------- fp32 -> bf16, x + 4 weight matrices in one launch ----------------
__global__ __launch_bounds__(256) void cvt_all(const float* __restrict__ x,
                                               const float* __restrict__ W0,
                                               const float* __restrict__ W1,
                                               const float* __restrict__ W2,
                                               const float* __restrict__ W3,
                                               u16* __restrict__ xb,
                                               u16* __restrict__ wb) {
  const int i = blockIdx.x * 256 + threadIdx.x;  // 8-elem units
  const float* src;
  u16* dst;
  if (i < 524288) {            // x: 4 Mi elements
    src = x + (size_t)i * 8;
    dst = xb + (size_t)i * 8;
  } else {                     // weights: 4 x 1 Mi, contiguous dst
    const int j = i - 524288;
    const int sel = j >> 17;   // block-uniform
    const float* W = sel == 0 ? W0 : sel == 1 ? W1 : sel == 2 ? W2 : W3;
    src = W + (size_t)(j & 131071) * 8;
    dst = wb + (size_t)j * 8;
  }
  const float4* s = (const float4*)src;
  float4 f0 = s[0], f1 = s[1];
  u16x8 p;
  p[0] = f2bf(f0.x); p[1] = f2bf(f0.y); p[2] = f2bf(f0.z); p[3] = f2bf(f0.w);
  p[4] = f2bf(f1.x); p[5] = f2bf(f1.y); p[6] = f2bf(f1.z); p[7] = f2bf(f1.w);
  *(u16x8*)dst = p;
}

// ---------------- GEMM (bf16, gld16 staging): C = A[M,K] * B[N,K]^T + bias ----------
// OMODE 3 (BN=128): fused QKV epilogue, N=3072. sel=bn>>10: Q (scaled by QSCALE), K
//   natural bf16; V -> Vt[b,h,s,t]. OMODE 2 (BN=64): f32 natural, bias b0.
template <int OMODE, int BN>
__global__ __launch_bounds__(256) void gemm16(const u16* __restrict__ A,
                                              const u16* __restrict__ Bm,
                                              const float* __restrict__ b0,
                                              const float* __restrict__ b1,
                                              const float* __restrict__ b2,
                                              void* __restrict__ C0,
                                              int M, int N, int K) {
  constexpr int NF = BN / 32;  // n-frags per wave
  __shared__ u16 As[128 * 32];
  __shared__ u16 Bs[BN * 32];
  const int bm = blockIdx.x * 128;
  const int bn = blockIdx.y * BN;
  const int tid = threadIdx.x;
  const int w = tid >> 6, lane = tid & 63;
  const int wr = (w >> 1) * 64, wc = (w & 1) * (BN / 2);
  const int lr = lane & 15, g = lane >> 4;
  const int lk = g * 8;
  const int srow = lane >> 2, scol = (lane & 3) * 8;

  f32x4 acc[4][NF] = {};

  for (int k0 = 0; k0 < K; k0 += 32) {
#pragma unroll
    for (int i = 0; i < 2; ++i) {
      const int rbase = (i * 4 + w) * 16;
      gld16(A + (size_t)(bm + rbase + srow) * K + k0 + scol, &As[rbase * 32]);
    }
#pragma unroll
    for (int i = 0; i < BN / 64; ++i) {
      const int rbase = (i * 4 + w) * 16;
      gld16(Bm + (size_t)(bn + rbase + srow) * K + k0 + scol, &Bs[rbase * 32]);
    }
    asm volatile("s_waitcnt vmcnt(0)" ::: "memory");
    __syncthreads();
    bf16x8 af[4], bfr[NF];
#pragma unroll
    for (int m = 0; m < 4; ++m)
      af[m] = *(const bf16x8*)&As[(wr + m * 16 + lr) * 32 + lk];
#pragma unroll
    for (int n = 0; n < NF; ++n)
      bfr[n] = *(const bf16x8*)&Bs[(wc + n * 16 + lr) * 32 + lk];
    __builtin_amdgcn_s_setprio(1);
#pragma unroll
    for (int m = 0; m < 4; ++m)
#pragma unroll
      for (int n = 0; n < NF; ++n)
        acc[m][n] = MFMA(af[m], bfr[n], acc[m][n]);
    __builtin_amdgcn_s_setprio(0);
    __syncthreads();
  }

  const int sel = (OMODE == 2) ? 0 : (bn >> 10);
  const float* bp = (OMODE == 2) ? b0 : (sel == 0 ? b0 : sel == 1 ? b1 : b2);
#pragma unroll
  for (int n = 0; n < NF; ++n) {
    const int col = bn + wc + n * 16 + lr;
    const float bv = bp[(OMODE == 2) ? col : (col & 1023)];
#pragma unroll
    for (int m = 0; m < 4; ++m) {
#pragma unroll
      for (int r = 0; r < 4; ++r) {
        const int row = bm + wr + m * 16 + g * 4 + r;
        float v = acc[m][n][r] + bv;
        if (OMODE == 2) {
          ((float*)C0)[(size_t)row * N + col] = v;
        } else {
          u16* dst = (u16*)C0;
          const int cc = col & 1023;
          if (sel == 2) {
            const int bb = row >> 11, t = row & 2047, hh = cc >> 6, ss = cc & 63;
            dst[(size_t)2 * MKC + (((size_t)(bb * H_ + hh) * S_ + ss) << 11) + t] = f2bf(v);
          } else {
            if (sel == 0) v *= QSCALE;
            dst[(size_t)sel * MKC + (size_t)row * 1024 + cc] = f2bf(v);
          }
        }
      }
    }
  }
}

// ---------------- Flash attention, swapped-QK^T, KVBLK=64, K+V in LDS ----------------
// Q pre-scaled by log2(e)/32 -> logits in log2-domain, exp == v_exp_f32.
// Grid: x = bh (32), y -> qtile via f(y) so each CU's resident blocks have
// constant total causal work and shared bh (L2-hot K/V).
__global__ __launch_bounds__(256) void attn_fwd(const u16* __restrict__ Q,
                                                const u16* __restrict__ Kb,
                                                const u16* __restrict__ Vt,
                                                u16* __restrict__ O) {
  __shared__ u16 Ks[2][64 * 64];   // rows 128 B (8 x 16B slots), XOR-swizzled
  __shared__ u16 Vs[2][64 * 64];   // [s(64)][t(64)], same swizzle
  __shared__ u32 Ps[4][16 * 32];
  const int tid = threadIdx.x;
  const int w = tid >> 6, lane = tid & 63;
  const int qh = lane & 15;
  const int g = lane >> 4;
  const int bh = blockIdx.x;
  const int b = bh >> 4, h = bh & 15;
  const int yy = blockIdx.y, t7 = yy & 7, kq = yy >> 3;
  const int qtile = (kq == 0) ? t7 : (kq == 1) ? (15 - t7) : (kq == 2) ? (16 + t7) : (31 - t7);
  const int qb = qtile * 64;
  const int qw = qb + w * 16;
  const int myq = qw + qh;

  const size_t qoff = (size_t)(b * T_ + qw + qh) * K_ + h * S_ + g * 8;
  const bf16x8 bq0 = *(const bf16x8*)(Q + qoff);
  const bf16x8 bq1 = *(const bf16x8*)(Q + qoff + 32);

  const int srow = lane >> 3;
  const int sslot = (lane & 7) ^ srow;
  auto stage = [&](int buf, int k0) {
#pragma unroll
    for (int i = 0; i < 2; ++i) {
      const int rbase = w * 16 + i * 8;
      gld16(Kb + (size_t)(b * T_ + k0 + rbase + srow) * K_ + h * S_ + sslot * 8,
            &Ks[buf][rbase * 64]);
      gld16(Vt + (size_t)(bh * S_ + rbase + srow) * T_ + k0 + sslot * 8,
            &Vs[buf][rbase * 64]);
    }
  };

  const int nk = qtile + 1;
  stage(0, 0);
  asm volatile("s_waitcnt vmcnt(0)" ::: "memory");
  __syncthreads();

  float m = -INFINITY, lsum = 0.f;
  f32x4 o[4] = {};
  u32* pr = &Ps[w][qh * 32];
  const int sx = (qh & 7) << 2;
  const int ksw = qh & 7;

  for (int kt = 0; kt < nk; ++kt) {
    const int k0 = kt * 64;
    const int cur = kt & 1;
    if (kt + 1 < nk) stage(cur ^ 1, k0 + 64);

    // QK^T (swapped): S^T[kv][q], logits already log2-scaled
    f32x4 s[4] = {};
    __builtin_amdgcn_s_setprio(1);
#pragma unroll
    for (int a = 0; a < 4; ++a) {
      const u16* kr = &Ks[cur][(a * 16 + qh) * 64];
      const bf16x8 kf0 = *(const bf16x8*)(kr + ((g ^ ksw) * 8));
      const bf16x8 kf1 = *(const bf16x8*)(kr + (((4 + g) ^ ksw) * 8));
      s[a] = MFMA(kf0, bq0, s[a]);
      s[a] = MFMA(kf1, bq1, s[a]);
    }
    __builtin_amdgcn_s_setprio(0);

    float p[4][4];
    float vmax = -INFINITY;
    if (k0 + 63 > qw) {  // wave-uniform: tile needs causal masking
#pragma unroll
      for (int a = 0; a < 4; ++a)
#pragma unroll
        for (int r = 0; r < 4; ++r) {
          const int kv = k0 + a * 16 + g * 4 + r;
          const float v = (kv <= myq) ? s[a][r] : -INFINITY;
          p[a][r] = v;
          vmax = fmaxf(vmax, v);
        }
    } else {
#pragma unroll
      for (int a = 0; a < 4; ++a)
#pragma unroll
        for (int r = 0; r < 4; ++r) {
          p[a][r] = s[a][r];
          vmax = fmaxf(vmax, s[a][r]);
        }
    }
    vmax = fmaxf(vmax, __shfl_xor(vmax, 16));
    vmax = fmaxf(vmax, __shfl_xor(vmax, 32));

    // defer-max (T13): threshold 8 nats = 11.5 bits
    if (__any(vmax > m + 11.5f)) {
      const float mnew = fmaxf(m, vmax);
      const float alpha = __builtin_amdgcn_exp2f(m - mnew);
      m = mnew;
      lsum *= alpha;
      float aR[4];
#pragma unroll
      for (int r = 0; r < 4; ++r) aR[r] = __shfl(alpha, 4 * g + r);
#pragma unroll
      for (int n = 0; n < 4; ++n)
#pragma unroll
        for (int r = 0; r < 4; ++r) o[n][r] *= aR[r];
    }

    float ls = 0.f;
#pragma unroll
    for (int a = 0; a < 4; ++a)
#pragma unroll
      for (int r = 0; r < 4; ++r) {
        p[a][r] = __builtin_amdgcn_exp2f(p[a][r] - m);
        ls += p[a][r];
      }
    ls += __shfl_xor(ls, 16);
    ls += __shfl_xor(ls, 32);
    lsum += ls;

    // P -> per-wave LDS (swizzled) via cvt_pk, read back as A-frags
#pragma unroll
    for (int a = 0; a < 4; ++a) {
      u32 u0, u1;
      asm("v_cvt_pk_bf16_f32 %0, %1, %2" : "=v"(u0) : "v"(p[a][0]), "v"(p[a][1]));
      asm("v_cvt_pk_bf16_f32 %0, %1, %2" : "=v"(u1) : "v"(p[a][2]), "v"(p[a][3]));
      uint2 uu; uu.x = u0; uu.y = u1;
      *(uint2*)&pr[(8 * a + 2 * g) ^ sx] = uu;
    }
    __builtin_amdgcn_s_setprio(1);
#pragma unroll
    for (int c = 0; c < 2; ++c) {
      const bf16x8 pa = *(const bf16x8*)&pr[(16 * c + 4 * g) ^ sx];
#pragma unroll
      for (int n = 0; n < 4; ++n) {
        const bf16x8 vf =
            *(const bf16x8*)(&Vs[cur][(16 * n + qh) * 64] + (((c * 4 + g) ^ ksw) * 8));
        o[n] = MFMA(pa, vf, o[n]);
      }
    }
    __builtin_amdgcn_s_setprio(0);

    asm volatile("s_waitcnt vmcnt(0)" ::: "memory");
    __syncthreads();
  }

  const float inv = 1.f / lsum;
  float iR[4];
#pragma unroll
  for (int r = 0; r < 4; ++r) iR[r] = __shfl(inv, 4 * g + r);
#pragma unroll
  for (int r = 0; r < 4; ++r) {
    const size_t row = (size_t)(b * T_ + qw + 4 * g + r);
#pragma unroll
    for (int n = 0; n < 4; ++n)
      O[row * K_ + h * S_ + n * 16 + qh] = f2bf(o[n][r] * iR[r]);
  }
}

extern "C" void kernel_launch(void* const* d_in, const int* in_sizes, int n_in,
                              void* d_out, int out_size, void* d_ws, size_t ws_size,
                              hipStream_t stream) {
  (void)in_sizes; (void)n_in; (void)out_size; (void)ws_size;
  const float* x  = (const float*)d_in[0];
  const float* Wq = (const float*)d_in[1];
  const float* bq = (const float*)d_in[2];
  const float* Wk = (const float*)d_in[3];
  const float* bk = (const float*)d_in[4];
  const float* Wv = (const float*)d_in[5];
  const float* bv = (const float*)d_in[6];
  const float* Wo = (const float*)d_in[7];
  const float* bo = (const float*)d_in[8];
  float* out = (float*)d_out;

  const size_t MK = (size_t)MKC;
  const size_t WK = (size_t)K_ * K_;
  u16* Qb  = (u16*)d_ws;      // Q | K | Vt contiguous (gemm16<3> dst)
  u16* Kbf = Qb + MK;
  u16* Vtb = Kbf + MK;
  u16* AO  = Vtb + MK;
  u16* xb  = AO + MK;
  u16* Wqkv = xb + MK;        // Wq|Wk|Wv|Wo bf16 contiguous
  u16* Wob  = Wqkv + 3 * WK;

  dim3 blk(256);
  cvt_all<<<dim3(4096), blk, 0, stream>>>(x, Wq, Wk, Wv, Wo, xb, Wqkv);
  gemm16<3, 128><<<dim3(32, 24), blk, 0, stream>>>(xb, Wqkv, bq, bk, bv, Qb,
                                                   B_ * T_, 3 * K_, K_);
  attn_fwd<<<dim3(B_ * H_, T_ / 64), blk, 0, stream>>>(Qb, Kbf, Vtb, AO);
  gemm16<2, 64><<<dim3(32, 16), blk, 0, stream>>>(AO, Wob, bo, bo, bo, out,
                                                  B_ * T_, K_, K_);
}